// Round 14
// baseline (358.518 us; speedup 1.0000x reference)
//
#include <hip/hip_runtime.h>
#include <hip/hip_bf16.h>

#define N_NODES 10000
#define N_EDGES 160000
#define DD      256   // hidden dim

typedef __bf16 bf16x8 __attribute__((ext_vector_type(8)));
typedef float  f32x4  __attribute__((ext_vector_type(4)));

// ---------------------------------------------------------------------------
// Fused weight prep: all five bf16 weight layouts in one launch.
// ---------------------------------------------------------------------------
__global__ void prep_weights_kernel(
    const float* __restrict__ Wn, const float* __restrict__ We,
    const float* __restrict__ Wnt, const float* __restrict__ Wpa,
    const float* __restrict__ Wsa, const float* __restrict__ Wet,
    __hip_bfloat16* __restrict__ Wn_t, __hip_bfloat16* __restrict__ We_t,
    __hip_bfloat16* __restrict__ Wnt_t, __hip_bfloat16* __restrict__ We_edge,
    __hip_bfloat16* __restrict__ Wn_node) {
  int idx = blockIdx.x * 256 + threadIdx.x;
  if (idx < 65536) {  // Wn_t [256][256]
    const int n = idx >> 8, k = idx & 255;
    Wn_t[idx] = __float2bfloat16(Wn[k * 256 + n]);
    return;
  }
  idx -= 65536;
  if (idx < 32768) {  // We_t [256][128]
    const int n = idx >> 7, k = idx & 127;
    We_t[idx] = __float2bfloat16(We[k * 256 + n]);
    return;
  }
  idx -= 32768;
  if (idx < 196608) {  // Wnt_t [256][768]
    const int n = idx / 768, k = idx % 768;
    Wnt_t[idx] = __float2bfloat16(Wnt[k * 256 + n]);
    return;
  }
  idx -= 196608;
  if (idx < 196608) {  // We_edge [768][256]
    const int n = idx >> 8, k = idx & 255;
    float v;
    if (n < 256)      v = Wpa[(256 + k) * 256 + n];
    else if (n < 512) v = Wsa[(256 + k) * 256 + (n - 256)];
    else              v = Wet[(256 + k) * 256 + (n - 512)];
    We_edge[idx] = __float2bfloat16(v);
    return;
  }
  idx -= 196608;
  if (idx < 262144) {  // Wn_node [1024][256]
    const int n = idx >> 8, k = idx & 255;
    float v;
    if (n < 256)      v = Wpa[k * 256 + n];
    else if (n < 512) v = Wsa[k * 256 + (n - 256)];
    else if (n < 768) v = Wet[k * 256 + (n - 512)];
    else              v = Wet[(512 + k) * 256 + (n - 768)];
    Wn_node[idx] = __float2bfloat16(v);
  }
}

// ---------------------------------------------------------------------------
// CSR build
// ---------------------------------------------------------------------------
__global__ void count_kernel(const int* __restrict__ src, const int* __restrict__ dst,
                             int* __restrict__ cnt_out, int* __restrict__ cnt_in) {
  const int e = blockIdx.x * 256 + threadIdx.x;
  if (e < N_EDGES) {
    atomicAdd(&cnt_out[src[e]], 1);
    atomicAdd(&cnt_in[dst[e]], 1);
  }
}

__global__ __launch_bounds__(256) void scan2_kernel(
    const int* __restrict__ cnt_in, const int* __restrict__ cnt_out,
    int* __restrict__ offs_in, int* __restrict__ offs_out) {
  const int* cnt = blockIdx.x ? cnt_out : cnt_in;
  int* offs      = blockIdx.x ? offs_out : offs_in;
  const int n = N_NODES;
  __shared__ int part[256];
  const int t  = threadIdx.x;
  const int lo = t * 40;
  const int hi = (lo + 40 < n) ? lo + 40 : n;
  int s = 0;
  for (int i = lo; i < hi; ++i) s += cnt[i];
  part[t] = s;
  __syncthreads();
  for (int off = 1; off < 256; off <<= 1) {
    int v = (t >= off) ? part[t - off] : 0;
    __syncthreads();
    part[t] += v;
    __syncthreads();
  }
  int run = (t == 0) ? 0 : part[t - 1];
  for (int i = lo; i < hi; ++i) { offs[i] = run; run += cnt[i]; }
  if (t == 255) offs[n] = run;
}

__global__ void fill_kernel(const int* __restrict__ src, const int* __restrict__ dst,
                            const int* __restrict__ offs_out, const int* __restrict__ offs_in,
                            int* __restrict__ cur_out, int* __restrict__ cur_in,
                            int* __restrict__ pos_out, int* __restrict__ pos_in) {
  const int e = blockIdx.x * 256 + threadIdx.x;
  if (e < N_EDGES) {
    const int u = src[e];
    pos_out[e] = offs_out[u] + atomicAdd(&cur_out[u], 1);
    const int v = dst[e];
    pos_in[e] = offs_in[v] + atomicAdd(&cur_in[v], 1);
  }
}

// ---------------------------------------------------------------------------
// Generic MFMA GEMM, 8-wave / 512-thread blocks.
// ---------------------------------------------------------------------------
template <bool RELU, bool F32OUT, bool A_F32>
__global__ __launch_bounds__(512, 4) void gemm_mfma_kernel(
    const void* __restrict__ Av, const __hip_bfloat16* __restrict__ Wt,
    const float* __restrict__ bias, float* __restrict__ outf,
    __hip_bfloat16* __restrict__ outb, int M, int Ksteps, int ldo) {
  __shared__ char sA[2][16384];
  __shared__ char sW[2][16384];

  const int K    = Ksteps * 64;
  const int row0 = blockIdx.x * 128;
  const int nt   = blockIdx.y;

  const int tid  = threadIdx.x;
  const int lane = tid & 63;
  const int w    = tid >> 6;   // 0..7

  const int rsub  = lane >> 3;
  const int pslot = lane & 7;
  const int sslot = pslot ^ rsub;

  auto stage = [&](int b, int c) {
#pragma unroll
    for (int j = 0; j < 2; ++j) {
      const int r = w * 16 + j * 8 + rsub;   // 0..127
      int ar = row0 + r;
      if (ar >= M) ar = M - 1;
      if constexpr (A_F32) {
        const float* gp = (const float*)Av + (size_t)ar * K + c * 64 + sslot * 8;
        const f32x4 lo = *(const f32x4*)gp;
        const f32x4 hi = *(const f32x4*)(gp + 4);
        union { __hip_bfloat16 h[8]; bf16x8 v; } pk;
#pragma unroll
        for (int q = 0; q < 4; ++q) pk.h[q] = __float2bfloat16(lo[q]);
#pragma unroll
        for (int q = 0; q < 4; ++q) pk.h[4 + q] = __float2bfloat16(hi[q]);
        *(bf16x8*)&sA[b][r * 128 + pslot * 16] = pk.v;
      } else {
        const __hip_bfloat16* gp =
            (const __hip_bfloat16*)Av + (size_t)ar * K + c * 64 + sslot * 8;
        __builtin_amdgcn_global_load_lds(
            (const __attribute__((address_space(1))) void*)gp,
            (__attribute__((address_space(3))) void*)&sA[b][(w * 16 + j * 8) * 128],
            16, 0, 0);
      }
      const __hip_bfloat16* wp = Wt + (size_t)(nt * 128 + r) * K + c * 64 + sslot * 8;
      __builtin_amdgcn_global_load_lds(
          (const __attribute__((address_space(1))) void*)wp,
          (__attribute__((address_space(3))) void*)&sW[b][(w * 16 + j * 8) * 128],
          16, 0, 0);
    }
  };

  const int wm = (w >> 1) * 32;
  const int wn = (w & 1) * 64;

  f32x4 acc[2][4];
#pragma unroll
  for (int i = 0; i < 2; ++i)
#pragma unroll
    for (int j = 0; j < 4; ++j) acc[i][j] = (f32x4)0.f;

  stage(0, 0);
  asm volatile("s_waitcnt vmcnt(0)");
  __syncthreads();

  int buf = 0;
  for (int c = 0; c < Ksteps; ++c) {
    if (c + 1 < Ksteps) stage(buf ^ 1, c + 1);
#pragma unroll
    for (int kk = 0; kk < 2; ++kk) {
      bf16x8 av[2], bv[4];
#pragma unroll
      for (int i = 0; i < 2; ++i) {
        const int row  = wm + i * 16 + (lane & 15);
        const int boff = row * 128 + ((kk * 64 + (lane >> 4) * 16) ^ ((row & 7) << 4));
        av[i] = *(const bf16x8*)&sA[buf][boff];
      }
#pragma unroll
      for (int j = 0; j < 4; ++j) {
        const int nrow = wn + j * 16 + (lane & 15);
        const int boff = nrow * 128 + ((kk * 64 + (lane >> 4) * 16) ^ ((nrow & 7) << 4));
        bv[j] = *(const bf16x8*)&sW[buf][boff];
      }
#pragma unroll
      for (int i = 0; i < 2; ++i)
#pragma unroll
        for (int j = 0; j < 4; ++j)
          acc[i][j] = __builtin_amdgcn_mfma_f32_16x16x32_bf16(av[i], bv[j], acc[i][j], 0, 0, 0);
    }
    __syncthreads();
    buf ^= 1;
  }

#pragma unroll
  for (int i = 0; i < 2; ++i) {
    const int row = row0 + wm + i * 16 + ((lane >> 4) << 2);
#pragma unroll
    for (int j = 0; j < 4; ++j) {
      const int col = nt * 128 + wn + j * 16 + (lane & 15);
      const float bb = bias ? bias[col] : 0.f;
#pragma unroll
      for (int r = 0; r < 4; ++r) {
        if (row + r < M) {
          float v = acc[i][j][r] + bb;
          if (RELU) v = v > 0.f ? v : 0.f;
          if (F32OUT) outf[(size_t)(row + r) * ldo + col] = v;
          else        outb[(size_t)(row + r) * ldo + col] = __float2bfloat16(v);
        }
      }
    }
  }
}

// ---------------------------------------------------------------------------
// Edge kernel v4: 32-edge tiles, 3 blocks/CU (24 waves), pretrans_e fused.
// Wave grid 2x4: wm in {0,16}, wn in {0,32,64,96}.
// Phase A: ef tile [32][128] f32 reg-staged -> bf16 swizzled sA[0:2];
//   We_t staged via global_load_lds (2 halves); pre_e = relu(ef@We_t^T+be)
//   ds_written into swizzled sA[4] c-blocks.
// Phase B: 6-nt loop vs We_edge (W dbuf streamed), epilogue nodeP add + relu
//   + msg store (CSR positions) / edge_out store.  MSG=false -> f32 atomics.
// ---------------------------------------------------------------------------
template <bool MSG>
__global__ __launch_bounds__(512, 6) void edge_mfma_kernel(
    const float* __restrict__ ef,              // edge_feat [E][128] f32
    const __hip_bfloat16* __restrict__ We_t,   // [256 n][128 k]
    const float* __restrict__ be,
    const __hip_bfloat16* __restrict__ We,     // We_edge [768][256]
    const __hip_bfloat16* __restrict__ nodeP,
    const int* __restrict__ src, const int* __restrict__ dst,
    const int* __restrict__ pos_in, const int* __restrict__ pos_out,
    const float* __restrict__ bpa, const float* __restrict__ bsa,
    const float* __restrict__ bet,
    float* __restrict__ agg_p, float* __restrict__ agg_s,
    __hip_bfloat16* __restrict__ msg_p, __hip_bfloat16* __restrict__ msg_s,
    float* __restrict__ edge_out) {
  __shared__ char sA[4][4096];    // pre_e tile: 4 c-blocks of [32 rows][128B]
  __shared__ char sW[2][16384];
  __shared__ int sSrc[32], sDst[32], sPin[32], sPout[32];

  const int et = blockIdx.x;
  const int e0 = et * 32;

  const int tid  = threadIdx.x;
  const int lane = tid & 63;
  const int w    = tid >> 6;

  if (tid < 32)        sSrc[tid] = src[e0 + tid];
  else if (tid < 64)   sDst[tid - 32] = dst[e0 + tid - 32];
  else if (tid < 96)  { if (MSG) sPin[tid - 64]  = pos_in[e0 + tid - 64]; }
  else if (tid < 128) { if (MSG) sPout[tid - 96] = pos_out[e0 + tid - 96]; }

  const int rsub  = lane >> 3;
  const int pslot = lane & 7;
  const int sslot = pslot ^ rsub;

  const int wm = (w >> 2) * 16;   // 0,16
  const int wn = (w & 3) * 32;    // 0,32,64,96

  // ---- Phase A step 1: reg-stage ef tile -> bf16 swizzled into sA[0],sA[1]
  {
    const int r  = tid >> 4;          // 0..31
    const int s  = tid & 15;          // 0..15 (8 f32 each)
    const int kb = s >> 3;            // 0/1
    const int ss = s & 7;
    const float* gp = ef + (size_t)(e0 + r) * 128 + s * 8;
    const f32x4 lo = *(const f32x4*)gp;
    const f32x4 hi = *(const f32x4*)(gp + 4);
    union { __hip_bfloat16 h[8]; bf16x8 v; } pk;
#pragma unroll
    for (int q = 0; q < 4; ++q) pk.h[q] = __float2bfloat16(lo[q]);
#pragma unroll
    for (int q = 0; q < 4; ++q) pk.h[4 + q] = __float2bfloat16(hi[q]);
    *(bf16x8*)&sA[kb][r * 128 + ((ss * 16) ^ ((r & 7) << 4))] = pk.v;
  }

  // Stage We_t half h: rows [h*128, h*128+128), kb0 -> sW[0], kb1 -> sW[1]
  auto stageWt = [&](int h) {
#pragma unroll
    for (int j = 0; j < 2; ++j) {
      const int r = w * 16 + j * 8 + rsub;   // 0..127
#pragma unroll
      for (int kb = 0; kb < 2; ++kb) {
        const __hip_bfloat16* gp =
            We_t + (size_t)(h * 128 + r) * 128 + kb * 64 + sslot * 8;
        __builtin_amdgcn_global_load_lds(
            (const __attribute__((address_space(1))) void*)gp,
            (__attribute__((address_space(3))) void*)&sW[kb][(w * 16 + j * 8) * 128],
            16, 0, 0);
      }
    }
  };

  auto stageW = [&](int b, int t) {   // We_edge panel t = nt*4+c
    const int nt = t >> 2, c = t & 3;
#pragma unroll
    for (int j = 0; j < 2; ++j) {
      const int r = w * 16 + j * 8 + rsub;
      const __hip_bfloat16* wp = We + (size_t)(nt * 128 + r) * 256 + c * 64 + sslot * 8;
      __builtin_amdgcn_global_load_lds(
          (const __attribute__((address_space(1))) void*)wp,
          (__attribute__((address_space(3))) void*)&sW[b][(w * 16 + j * 8) * 128],
          16, 0, 0);
    }
  };

  // ---- Phase A: two passes (output col halves), K=128 each
  f32x4 accA0[2], accA1[2];
#pragma unroll
  for (int j = 0; j < 2; ++j) { accA0[j] = (f32x4)0.f; accA1[j] = (f32x4)0.f; }

  stageWt(0);
  asm volatile("s_waitcnt vmcnt(0)");
  __syncthreads();

#pragma unroll
  for (int kb = 0; kb < 2; ++kb) {
#pragma unroll
    for (int kk = 0; kk < 2; ++kk) {
      const int row  = wm + (lane & 15);
      const int aoff = row * 128 + ((kk * 64 + (lane >> 4) * 16) ^ ((row & 7) << 4));
      const bf16x8 av = *(const bf16x8*)&sA[kb][aoff];
#pragma unroll
      for (int j = 0; j < 2; ++j) {
        const int nrow = wn + j * 16 + (lane & 15);
        const int boff = nrow * 128 + ((kk * 64 + (lane >> 4) * 16) ^ ((nrow & 7) << 4));
        const bf16x8 bv = *(const bf16x8*)&sW[kb][boff];
        accA0[j] = __builtin_amdgcn_mfma_f32_16x16x32_bf16(av, bv, accA0[j], 0, 0, 0);
      }
    }
  }
  __syncthreads();
  stageWt(1);
  asm volatile("s_waitcnt vmcnt(0)");
  __syncthreads();
#pragma unroll
  for (int kb = 0; kb < 2; ++kb) {
#pragma unroll
    for (int kk = 0; kk < 2; ++kk) {
      const int row  = wm + (lane & 15);
      const int aoff = row * 128 + ((kk * 64 + (lane >> 4) * 16) ^ ((row & 7) << 4));
      const bf16x8 av = *(const bf16x8*)&sA[kb][aoff];
#pragma unroll
      for (int j = 0; j < 2; ++j) {
        const int nrow = wn + j * 16 + (lane & 15);
        const int boff = nrow * 128 + ((kk * 64 + (lane >> 4) * 16) ^ ((nrow & 7) << 4));
        const bf16x8 bv = *(const bf16x8*)&sW[kb][boff];
        accA1[j] = __builtin_amdgcn_mfma_f32_16x16x32_bf16(av, bv, accA1[j], 0, 0, 0);
      }
    }
  }
  __syncthreads();          // all reads of ef-tile (sA) and sW done

  stageW(0, 0);             // first Phase-B panel into sW[0]

  // write pre_e results (bias+relu+bf16) into swizzled sA c-blocks
  {
    const int rowb = wm + ((lane >> 4) << 2);
#pragma unroll
    for (int h = 0; h < 2; ++h) {
#pragma unroll
      for (int j = 0; j < 2; ++j) {
        const int col  = h * 128 + wn + j * 16 + (lane & 15);  // 0..255
        const float bb = be[col];
        const int c    = col >> 6;
        const int cb2  = (col & 63) * 2;
#pragma unroll
        for (int r = 0; r < 4; ++r) {
          const int row = rowb + r;
          float v = (h == 0 ? accA0[j][r] : accA1[j][r]) + bb;
          v = v > 0.f ? v : 0.f;
          *(__hip_bfloat16*)&sA[c][row * 128 + (cb2 ^ ((row & 7) << 4))] =
              __float2bfloat16(v);
        }
      }
    }
  }

  asm volatile("s_waitcnt vmcnt(0)");
  __syncthreads();

  // ---- Phase B: 6-nt main loop ----
  int buf = 0;
  for (int nt = 0; nt < 6; ++nt) {
    const int mat = nt >> 1;
    f32x4 acc[2];
#pragma unroll
    for (int j = 0; j < 2; ++j) acc[j] = (f32x4)0.f;

#pragma unroll
    for (int c = 0; c < 4; ++c) {
      const int t = nt * 4 + c;
      if (t + 1 < 24) stageW(buf ^ 1, t + 1);
#pragma unroll
      for (int kk = 0; kk < 2; ++kk) {
        const int row  = wm + (lane & 15);
        const int aoff = row * 128 + ((kk * 64 + (lane >> 4) * 16) ^ ((row & 7) << 4));
        const bf16x8 av = *(const bf16x8*)&sA[c][aoff];
        bf16x8 bv[2];
#pragma unroll
        for (int j = 0; j < 2; ++j) {
          const int nrow = wn + j * 16 + (lane & 15);
          const int boff = nrow * 128 + ((kk * 64 + (lane >> 4) * 16) ^ ((nrow & 7) << 4));
          bv[j] = *(const bf16x8*)&sW[buf][boff];
        }
#pragma unroll
        for (int j = 0; j < 2; ++j)
          acc[j] = __builtin_amdgcn_mfma_f32_16x16x32_bf16(av, bv[j], acc[j], 0, 0, 0);
      }
      __syncthreads();
      buf ^= 1;
    }

    // epilogue (direct from acc)
    const int colbase = (nt & 1) * 128 + wn;
    const int lrow = wm + ((lane >> 4) << 2);
#pragma unroll
    for (int j = 0; j < 2; ++j) {
      const int col = colbase + j * 16 + (lane & 15);
      if (mat == 0) {
        const float bb = bpa[col];
#pragma unroll
        for (int r = 0; r < 4; ++r) {
          const int le = lrow + r;
          float v = acc[j][r] + bb +
                    __bfloat162float(nodeP[(size_t)sSrc[le] * 1024 + col]);
          v = v > 0.f ? v : 0.f;
          if (MSG) msg_p[(size_t)sPin[le] * 256 + col] = __float2bfloat16(v);
          else     atomicAdd(&agg_p[(size_t)sDst[le] * 256 + col], v);
        }
      } else if (mat == 1) {
        const float bb = bsa[col];
#pragma unroll
        for (int r = 0; r < 4; ++r) {
          const int le = lrow + r;
          float v = acc[j][r] + bb +
                    __bfloat162float(nodeP[(size_t)sDst[le] * 1024 + 256 + col]);
          v = v > 0.f ? v : 0.f;
          if (MSG) msg_s[(size_t)sPout[le] * 256 + col] = __float2bfloat16(v);
          else     atomicAdd(&agg_s[(size_t)sSrc[le] * 256 + col], v);
        }
      } else {
        const float bb = bet[col];
#pragma unroll
        for (int r = 0; r < 4; ++r) {
          const int le = lrow + r;
          float v = acc[j][r] + bb +
                    __bfloat162float(nodeP[(size_t)sSrc[le] * 1024 + 512 + col]) +
                    __bfloat162float(nodeP[(size_t)sDst[le] * 1024 + 768 + col]);
          edge_out[(size_t)(e0 + le) * 256 + col] = v;
        }
      }
    }
  }
}

// ---------------------------------------------------------------------------
// CSR-ordered segment-sum + nodeH assembly
// ---------------------------------------------------------------------------
__global__ __launch_bounds__(128) void agg_kernel(
    const __hip_bfloat16* __restrict__ msg_p, const __hip_bfloat16* __restrict__ msg_s,
    const __hip_bfloat16* __restrict__ pre_n,
    const int* __restrict__ offs_in, const int* __restrict__ offs_out,
    __hip_bfloat16* __restrict__ nodeH) {
  const int v    = blockIdx.x;
  const int wave = threadIdx.x >> 6;
  const int lane = threadIdx.x & 63;
  const int cg   = lane & 31;
  const int par  = lane >> 5;

  const int* offs = wave ? offs_out : offs_in;
  const __hip_bfloat16* msg = wave ? msg_s : msg_p;

  const int p0 = offs[v], p1 = offs[v + 1];
  float acc[8];
#pragma unroll
  for (int k = 0; k < 8; ++k) acc[k] = 0.f;

  for (int i = p0 + par; i < p1; i += 2) {
    const uint4 u = *(const uint4*)(msg + (size_t)i * 256 + cg * 8);
    const unsigned short* h = (const unsigned short*)&u;
#pragma unroll
    for (int k = 0; k < 8; ++k) acc[k] += __uint_as_float((unsigned)h[k] << 16);
  }
#pragma unroll
  for (int k = 0; k < 8; ++k) acc[k] += __shfl_xor(acc[k], 32);

  if (par == 0) {
    const int deg = p1 - p0;
    const float inv = 1.f / (float)(deg > 1 ? deg : 1);
    union { __hip_bfloat16 h[8]; uint4 u; } o;
#pragma unroll
    for (int k = 0; k < 8; ++k) o.h[k] = __float2bfloat16(acc[k] * inv);
    *(uint4*)(nodeH + (size_t)v * 768 + wave * 512 + cg * 8) = o.u;
  } else if (wave == 0) {
    const uint4 u = *(const uint4*)(pre_n + (size_t)v * 256 + cg * 8);
    *(uint4*)(nodeH + (size_t)v * 768 + 256 + cg * 8) = u;
  }
}

// ---------------------------------------------------------------------------
// fallback node prep (atomic path)
// ---------------------------------------------------------------------------
__global__ void node_prep_kernel(const float* __restrict__ agg_p,
                                 const float* __restrict__ agg_s,
                                 const __hip_bfloat16* __restrict__ pre_n,
                                 const int* __restrict__ cnt_in,
                                 const int* __restrict__ cnt_out,
                                 __hip_bfloat16* __restrict__ nodeH) {
  const int row = blockIdx.x;
  const int c   = threadIdx.x;
  const float di = (float)(cnt_in[row]  > 1 ? cnt_in[row]  : 1);
  const float dd = (float)(cnt_out[row] > 1 ? cnt_out[row] : 1);
  nodeH[(size_t)row * 768 + c]       = __float2bfloat16(agg_p[(size_t)row * 256 + c] / di);
  nodeH[(size_t)row * 768 + 256 + c] = pre_n[(size_t)row * 256 + c];
  nodeH[(size_t)row * 768 + 512 + c] = __float2bfloat16(agg_s[(size_t)row * 256 + c] / dd);
}

// ---------------------------------------------------------------------------
extern "C" void kernel_launch(void* const* d_in, const int* in_sizes, int n_in,
                              void* d_out, int out_size, void* d_ws, size_t ws_size,
                              hipStream_t stream) {
  const float* x         = (const float*)d_in[0];
  const float* edge_feat = (const float*)d_in[1];
  const int*   edge_idx  = (const int*)d_in[2];
  const float* Wn  = (const float*)d_in[3];
  const float* bn  = (const float*)d_in[4];
  const float* We  = (const float*)d_in[5];
  const float* be  = (const float*)d_in[6];
  const float* Wpa = (const float*)d_in[7];
  const float* bpa = (const float*)d_in[8];
  const float* Wsa = (const float*)d_in[9];
  const float* bsa = (const float*)d_in[10];
  const float* Wnt = (const float*)d_in[11];
  const float* bnt = (const float*)d_in[12];
  const float* Wet = (const float*)d_in[13];
  const float* bet = (const float*)d_in[14];

  const int* src = edge_idx;
  const int* dst = edge_idx + N_EDGES;

  float* node_out = (float*)d_out;
  float* edge_out = (float*)d_out + (size_t)N_NODES * DD;

  char* p = (char*)d_ws;
  auto alloc = [&](size_t bytes) -> void* {
    void* r = (void*)p;
    p += (bytes + 255) & ~(size_t)255;
    return r;
  };

  __hip_bfloat16* pre_n_bf = (__hip_bfloat16*)alloc((size_t)N_NODES * DD * 2);
  __hip_bfloat16* nodeH    = (__hip_bfloat16*)alloc((size_t)N_NODES * 768 * 2);
  __hip_bfloat16* nodeP    = (__hip_bfloat16*)alloc((size_t)N_NODES * 1024 * 2);
  __hip_bfloat16* We_edge  = (__hip_bfloat16*)alloc((size_t)768 * 256 * 2);
  __hip_bfloat16* Wn_node  = (__hip_bfloat16*)alloc((size_t)1024 * 256 * 2);
  __hip_bfloat16* Wn_t     = (__hip_bfloat16*)alloc((size_t)256 * 256 * 2);
  __hip_bfloat16* We_t     = (__hip_bfloat16*)alloc((size_t)256 * 128 * 2);
  __hip_bfloat16* Wnt_t    = (__hip_bfloat16*)alloc((size_t)256 * 768 * 2);
  int* csr_zero = (int*)alloc(4 * (size_t)N_NODES * 4);
  int* cnt_in   = csr_zero;
  int* cnt_out  = csr_zero + N_NODES;
  int* cur_in   = csr_zero + 2 * N_NODES;
  int* cur_out  = csr_zero + 3 * N_NODES;
  int* offs_in  = (int*)alloc(((size_t)N_NODES + 1) * 4);
  int* offs_out = (int*)alloc(((size_t)N_NODES + 1) * 4);
  int* pos_in   = (int*)alloc((size_t)N_EDGES * 4);
  int* pos_out  = (int*)alloc((size_t)N_EDGES * 4);

  const size_t msg_bytes = (size_t)N_EDGES * DD * 2;
  const size_t base_used = (size_t)(p - (char*)d_ws);
  const bool msg_mode = ws_size >= base_used + 2 * msg_bytes + 512;

  __hip_bfloat16* msg_p = nullptr;
  __hip_bfloat16* msg_s = nullptr;
  float* agg_p = nullptr;
  float* agg_s = nullptr;
  if (msg_mode) {
    msg_p = (__hip_bfloat16*)alloc(msg_bytes);
    msg_s = (__hip_bfloat16*)alloc(msg_bytes);
  } else {
    agg_p = (float*)alloc((size_t)N_NODES * DD * 4);
    agg_s = (float*)alloc((size_t)N_NODES * DD * 4);
  }

  hipMemsetAsync(csr_zero, 0, 4 * (size_t)N_NODES * 4, stream);
  if (!msg_mode)
    hipMemsetAsync(agg_p, 0, 2 * (size_t)N_NODES * DD * 4, stream);

  prep_weights_kernel<<<(753664 + 255) / 256, 256, 0, stream>>>(
      Wn, We, Wnt, Wpa, Wsa, Wet, Wn_t, We_t, Wnt_t, We_edge, Wn_node);

  count_kernel<<<(N_EDGES + 255) / 256, 256, 0, stream>>>(src, dst, cnt_out, cnt_in);
  if (msg_mode) {
    scan2_kernel<<<2, 256, 0, stream>>>(cnt_in, cnt_out, offs_in, offs_out);
    fill_kernel<<<(N_EDGES + 255) / 256, 256, 0, stream>>>(
        src, dst, offs_out, offs_in, cur_out, cur_in, pos_out, pos_in);
  }

  {
    dim3 g((N_NODES + 127) / 128, 2);
    gemm_mfma_kernel<true, false, true><<<g, 512, 0, stream>>>(
        x, Wn_t, bn, nullptr, pre_n_bf, N_NODES, 4, 256);
  }
  {
    dim3 g((N_NODES + 127) / 128, 8);
    gemm_mfma_kernel<false, false, false><<<g, 512, 0, stream>>>(
        pre_n_bf, Wn_node, nullptr, nullptr, nodeP, N_NODES, 4, 1024);
  }

  if (msg_mode) {
    edge_mfma_kernel<true><<<N_EDGES / 32, 512, 0, stream>>>(
        edge_feat, We_t, be, We_edge, nodeP, src, dst, pos_in, pos_out,
        bpa, bsa, bet, nullptr, nullptr, msg_p, msg_s, edge_out);
    agg_kernel<<<N_NODES, 128, 0, stream>>>(
        msg_p, msg_s, pre_n_bf, offs_in, offs_out, nodeH);
  } else {
    edge_mfma_kernel<false><<<N_EDGES / 32, 512, 0, stream>>>(
        edge_feat, We_t, be, We_edge, nodeP, src, dst, nullptr, nullptr,
        bpa, bsa, bet, agg_p, agg_s, nullptr, nullptr, edge_out);
    node_prep_kernel<<<N_NODES, 256, 0, stream>>>(
        agg_p, agg_s, pre_n_bf, cnt_in, cnt_out, nodeH);
  }

  {
    dim3 g((N_NODES + 127) / 128, 2);
    gemm_mfma_kernel<false, true, false><<<g, 512, 0, stream>>>(
        nodeH, Wnt_t, bnt, node_out, nullptr, N_NODES, 12, 256);
  }
}

// Round 15
// 342.635 us; speedup vs baseline: 1.0464x; 1.0464x over previous
//
#include <hip/hip_runtime.h>
#include <hip/hip_bf16.h>

#define N_NODES 10000
#define N_EDGES 160000
#define DD      256   // hidden dim

typedef __bf16 bf16x8 __attribute__((ext_vector_type(8)));
typedef float  f32x4  __attribute__((ext_vector_type(4)));

// ---------------------------------------------------------------------------
// Fused weight prep: all five bf16 weight layouts in one launch.
// ---------------------------------------------------------------------------
__global__ void prep_weights_kernel(
    const float* __restrict__ Wn, const float* __restrict__ We,
    const float* __restrict__ Wnt, const float* __restrict__ Wpa,
    const float* __restrict__ Wsa, const float* __restrict__ Wet,
    __hip_bfloat16* __restrict__ Wn_t, __hip_bfloat16* __restrict__ We_t,
    __hip_bfloat16* __restrict__ Wnt_t, __hip_bfloat16* __restrict__ We_edge,
    __hip_bfloat16* __restrict__ Wn_node) {
  int idx = blockIdx.x * 256 + threadIdx.x;
  if (idx < 65536) {  // Wn_t [256][256]
    const int n = idx >> 8, k = idx & 255;
    Wn_t[idx] = __float2bfloat16(Wn[k * 256 + n]);
    return;
  }
  idx -= 65536;
  if (idx < 32768) {  // We_t [256][128]
    const int n = idx >> 7, k = idx & 127;
    We_t[idx] = __float2bfloat16(We[k * 256 + n]);
    return;
  }
  idx -= 32768;
  if (idx < 196608) {  // Wnt_t [256][768]
    const int n = idx / 768, k = idx % 768;
    Wnt_t[idx] = __float2bfloat16(Wnt[k * 256 + n]);
    return;
  }
  idx -= 196608;
  if (idx < 196608) {  // We_edge [768][256]
    const int n = idx >> 8, k = idx & 255;
    float v;
    if (n < 256)      v = Wpa[(256 + k) * 256 + n];
    else if (n < 512) v = Wsa[(256 + k) * 256 + (n - 256)];
    else              v = Wet[(256 + k) * 256 + (n - 512)];
    We_edge[idx] = __float2bfloat16(v);
    return;
  }
  idx -= 196608;
  if (idx < 262144) {  // Wn_node [1024][256]
    const int n = idx >> 8, k = idx & 255;
    float v;
    if (n < 256)      v = Wpa[k * 256 + n];
    else if (n < 512) v = Wsa[k * 256 + (n - 256)];
    else if (n < 768) v = Wet[k * 256 + (n - 512)];
    else              v = Wet[(512 + k) * 256 + (n - 768)];
    Wn_node[idx] = __float2bfloat16(v);
  }
}

// ---------------------------------------------------------------------------
// CSR build
// ---------------------------------------------------------------------------
__global__ void count_kernel(const int* __restrict__ src, const int* __restrict__ dst,
                             int* __restrict__ cnt_out, int* __restrict__ cnt_in) {
  const int e = blockIdx.x * 256 + threadIdx.x;
  if (e < N_EDGES) {
    atomicAdd(&cnt_out[src[e]], 1);
    atomicAdd(&cnt_in[dst[e]], 1);
  }
}

__global__ __launch_bounds__(256) void scan2_kernel(
    const int* __restrict__ cnt_in, const int* __restrict__ cnt_out,
    int* __restrict__ offs_in, int* __restrict__ offs_out) {
  const int* cnt = blockIdx.x ? cnt_out : cnt_in;
  int* offs      = blockIdx.x ? offs_out : offs_in;
  const int n = N_NODES;
  __shared__ int part[256];
  const int t  = threadIdx.x;
  const int lo = t * 40;
  const int hi = (lo + 40 < n) ? lo + 40 : n;
  int s = 0;
  for (int i = lo; i < hi; ++i) s += cnt[i];
  part[t] = s;
  __syncthreads();
  for (int off = 1; off < 256; off <<= 1) {
    int v = (t >= off) ? part[t - off] : 0;
    __syncthreads();
    part[t] += v;
    __syncthreads();
  }
  int run = (t == 0) ? 0 : part[t - 1];
  for (int i = lo; i < hi; ++i) { offs[i] = run; run += cnt[i]; }
  if (t == 255) offs[n] = run;
}

__global__ void fill_kernel(const int* __restrict__ src, const int* __restrict__ dst,
                            const int* __restrict__ offs_out, const int* __restrict__ offs_in,
                            int* __restrict__ cur_out, int* __restrict__ cur_in,
                            int* __restrict__ pos_out, int* __restrict__ pos_in) {
  const int e = blockIdx.x * 256 + threadIdx.x;
  if (e < N_EDGES) {
    const int u = src[e];
    pos_out[e] = offs_out[u] + atomicAdd(&cur_out[u], 1);
    const int v = dst[e];
    pos_in[e] = offs_in[v] + atomicAdd(&cur_in[v], 1);
  }
}

// ---------------------------------------------------------------------------
// Generic MFMA GEMM, 8-wave / 512-thread blocks.
// ---------------------------------------------------------------------------
template <bool RELU, bool F32OUT, bool A_F32>
__global__ __launch_bounds__(512, 4) void gemm_mfma_kernel(
    const void* __restrict__ Av, const __hip_bfloat16* __restrict__ Wt,
    const float* __restrict__ bias, float* __restrict__ outf,
    __hip_bfloat16* __restrict__ outb, int M, int Ksteps, int ldo) {
  __shared__ char sA[2][16384];
  __shared__ char sW[2][16384];

  const int K    = Ksteps * 64;
  const int row0 = blockIdx.x * 128;
  const int nt   = blockIdx.y;

  const int tid  = threadIdx.x;
  const int lane = tid & 63;
  const int w    = tid >> 6;   // 0..7

  const int rsub  = lane >> 3;
  const int pslot = lane & 7;
  const int sslot = pslot ^ rsub;

  auto stage = [&](int b, int c) {
#pragma unroll
    for (int j = 0; j < 2; ++j) {
      const int r = w * 16 + j * 8 + rsub;   // 0..127
      int ar = row0 + r;
      if (ar >= M) ar = M - 1;
      if constexpr (A_F32) {
        const float* gp = (const float*)Av + (size_t)ar * K + c * 64 + sslot * 8;
        const f32x4 lo = *(const f32x4*)gp;
        const f32x4 hi = *(const f32x4*)(gp + 4);
        union { __hip_bfloat16 h[8]; bf16x8 v; } pk;
#pragma unroll
        for (int q = 0; q < 4; ++q) pk.h[q] = __float2bfloat16(lo[q]);
#pragma unroll
        for (int q = 0; q < 4; ++q) pk.h[4 + q] = __float2bfloat16(hi[q]);
        *(bf16x8*)&sA[b][r * 128 + pslot * 16] = pk.v;
      } else {
        const __hip_bfloat16* gp =
            (const __hip_bfloat16*)Av + (size_t)ar * K + c * 64 + sslot * 8;
        __builtin_amdgcn_global_load_lds(
            (const __attribute__((address_space(1))) void*)gp,
            (__attribute__((address_space(3))) void*)&sA[b][(w * 16 + j * 8) * 128],
            16, 0, 0);
      }
      const __hip_bfloat16* wp = Wt + (size_t)(nt * 128 + r) * K + c * 64 + sslot * 8;
      __builtin_amdgcn_global_load_lds(
          (const __attribute__((address_space(1))) void*)wp,
          (__attribute__((address_space(3))) void*)&sW[b][(w * 16 + j * 8) * 128],
          16, 0, 0);
    }
  };

  const int wm = (w >> 1) * 32;
  const int wn = (w & 1) * 64;

  f32x4 acc[2][4];
#pragma unroll
  for (int i = 0; i < 2; ++i)
#pragma unroll
    for (int j = 0; j < 4; ++j) acc[i][j] = (f32x4)0.f;

  stage(0, 0);
  asm volatile("s_waitcnt vmcnt(0)");
  __syncthreads();

  int buf = 0;
  for (int c = 0; c < Ksteps; ++c) {
    if (c + 1 < Ksteps) stage(buf ^ 1, c + 1);
#pragma unroll
    for (int kk = 0; kk < 2; ++kk) {
      bf16x8 av[2], bv[4];
#pragma unroll
      for (int i = 0; i < 2; ++i) {
        const int row  = wm + i * 16 + (lane & 15);
        const int boff = row * 128 + ((kk * 64 + (lane >> 4) * 16) ^ ((row & 7) << 4));
        av[i] = *(const bf16x8*)&sA[buf][boff];
      }
#pragma unroll
      for (int j = 0; j < 4; ++j) {
        const int nrow = wn + j * 16 + (lane & 15);
        const int boff = nrow * 128 + ((kk * 64 + (lane >> 4) * 16) ^ ((nrow & 7) << 4));
        bv[j] = *(const bf16x8*)&sW[buf][boff];
      }
#pragma unroll
      for (int i = 0; i < 2; ++i)
#pragma unroll
        for (int j = 0; j < 4; ++j)
          acc[i][j] = __builtin_amdgcn_mfma_f32_16x16x32_bf16(av[i], bv[j], acc[i][j], 0, 0, 0);
    }
    __syncthreads();
    buf ^= 1;
  }

#pragma unroll
  for (int i = 0; i < 2; ++i) {
    const int row = row0 + wm + i * 16 + ((lane >> 4) << 2);
#pragma unroll
    for (int j = 0; j < 4; ++j) {
      const int col = nt * 128 + wn + j * 16 + (lane & 15);
      const float bb = bias ? bias[col] : 0.f;
#pragma unroll
      for (int r = 0; r < 4; ++r) {
        if (row + r < M) {
          float v = acc[i][j][r] + bb;
          if (RELU) v = v > 0.f ? v : 0.f;
          if (F32OUT) outf[(size_t)(row + r) * ldo + col] = v;
          else        outb[(size_t)(row + r) * ldo + col] = __float2bfloat16(v);
        }
      }
    }
  }
}

// ---------------------------------------------------------------------------
// Edge kernel v3 (r13 revert — measured best), 64-edge tiles, 2 blocks/CU,
// pretrans_e fused as a proper LDS GEMM.
// ---------------------------------------------------------------------------
template <bool MSG>
__global__ __launch_bounds__(512, 4) void edge_mfma_kernel(
    const float* __restrict__ ef,              // edge_feat [E][128] f32
    const __hip_bfloat16* __restrict__ We_t,   // [256 n][128 k]
    const float* __restrict__ be,
    const __hip_bfloat16* __restrict__ We,     // We_edge [768][256]
    const __hip_bfloat16* __restrict__ nodeP,
    const int* __restrict__ src, const int* __restrict__ dst,
    const int* __restrict__ pos_in, const int* __restrict__ pos_out,
    const float* __restrict__ bpa, const float* __restrict__ bsa,
    const float* __restrict__ bet,
    float* __restrict__ agg_p, float* __restrict__ agg_s,
    __hip_bfloat16* __restrict__ msg_p, __hip_bfloat16* __restrict__ msg_s,
    float* __restrict__ edge_out) {
  __shared__ char sA[4][8192];    // pre_e tile: 4 c-blocks of [64 rows][128B]
  __shared__ char sW[2][16384];
  __shared__ int sSrc[64], sDst[64], sPin[64], sPout[64];

  const int et = blockIdx.x;
  const int e0 = et * 64;

  const int tid  = threadIdx.x;
  const int lane = tid & 63;
  const int w    = tid >> 6;

  if (tid < 64)        sSrc[tid] = src[e0 + tid];
  else if (tid < 128)  sDst[tid - 64] = dst[e0 + tid - 64];
  else if (tid < 192) { if (MSG) sPin[tid - 128]  = pos_in[e0 + tid - 128]; }
  else if (tid < 256) { if (MSG) sPout[tid - 192] = pos_out[e0 + tid - 192]; }

  const int rsub  = lane >> 3;
  const int pslot = lane & 7;
  const int sslot = pslot ^ rsub;

  const int wm = (w >> 1) * 16;   // Phase B row base: 0,16,32,48
  const int wn = (w & 1) * 64;

  // ---- Phase A step 1: reg-stage ef tile -> bf16 swizzled into sA[0],sA[1]
  {
    const int r  = tid >> 3;          // 0..63
    const int s0 = tid & 7;           // slots s0 and s0+8 of 16
#pragma unroll
    for (int t = 0; t < 2; ++t) {
      const int s  = s0 + t * 8;      // 0..15 (8 f32 each)
      const int kb = s >> 3;          // 0/1
      const int ss = s & 7;
      const float* gp = ef + (size_t)(e0 + r) * 128 + s * 8;
      const f32x4 lo = *(const f32x4*)gp;
      const f32x4 hi = *(const f32x4*)(gp + 4);
      union { __hip_bfloat16 h[8]; bf16x8 v; } pk;
#pragma unroll
      for (int q = 0; q < 4; ++q) pk.h[q] = __float2bfloat16(lo[q]);
#pragma unroll
      for (int q = 0; q < 4; ++q) pk.h[4 + q] = __float2bfloat16(hi[q]);
      *(bf16x8*)&sA[kb][r * 128 + ((ss * 16) ^ ((r & 7) << 4))] = pk.v;
    }
  }

  // Stage We_t half h: rows [h*128, h*128+128), kb0 -> sW[0], kb1 -> sW[1]
  auto stageWt = [&](int h) {
#pragma unroll
    for (int j = 0; j < 2; ++j) {
      const int r = w * 16 + j * 8 + rsub;   // 0..127
#pragma unroll
      for (int kb = 0; kb < 2; ++kb) {
        const __hip_bfloat16* gp =
            We_t + (size_t)(h * 128 + r) * 128 + kb * 64 + sslot * 8;
        __builtin_amdgcn_global_load_lds(
            (const __attribute__((address_space(1))) void*)gp,
            (__attribute__((address_space(3))) void*)&sW[kb][(w * 16 + j * 8) * 128],
            16, 0, 0);
      }
    }
  };

  auto stageW = [&](int b, int t) {   // We_edge panel t = nt*4+c
    const int nt = t >> 2, c = t & 3;
#pragma unroll
    for (int j = 0; j < 2; ++j) {
      const int r = w * 16 + j * 8 + rsub;
      const __hip_bfloat16* wp = We + (size_t)(nt * 128 + r) * 256 + c * 64 + sslot * 8;
      __builtin_amdgcn_global_load_lds(
          (const __attribute__((address_space(1))) void*)wp,
          (__attribute__((address_space(3))) void*)&sW[b][(w * 16 + j * 8) * 128],
          16, 0, 0);
    }
  };

  // ---- Phase A: two passes (output col halves), K=128 each
  f32x4 accA0[4], accA1[4];
#pragma unroll
  for (int j = 0; j < 4; ++j) { accA0[j] = (f32x4)0.f; accA1[j] = (f32x4)0.f; }

  stageWt(0);
  asm volatile("s_waitcnt vmcnt(0)");
  __syncthreads();

#pragma unroll
  for (int kb = 0; kb < 2; ++kb) {
#pragma unroll
    for (int kk = 0; kk < 2; ++kk) {
      const int row  = wm + (lane & 15);
      const int aoff = row * 128 + ((kk * 64 + (lane >> 4) * 16) ^ ((row & 7) << 4));
      const bf16x8 av = *(const bf16x8*)&sA[kb][aoff];
#pragma unroll
      for (int j = 0; j < 4; ++j) {
        const int nrow = wn + j * 16 + (lane & 15);
        const int boff = nrow * 128 + ((kk * 64 + (lane >> 4) * 16) ^ ((nrow & 7) << 4));
        const bf16x8 bv = *(const bf16x8*)&sW[kb][boff];
        accA0[j] = __builtin_amdgcn_mfma_f32_16x16x32_bf16(av, bv, accA0[j], 0, 0, 0);
      }
    }
  }
  __syncthreads();
  stageWt(1);
  asm volatile("s_waitcnt vmcnt(0)");
  __syncthreads();
#pragma unroll
  for (int kb = 0; kb < 2; ++kb) {
#pragma unroll
    for (int kk = 0; kk < 2; ++kk) {
      const int row  = wm + (lane & 15);
      const int aoff = row * 128 + ((kk * 64 + (lane >> 4) * 16) ^ ((row & 7) << 4));
      const bf16x8 av = *(const bf16x8*)&sA[kb][aoff];
#pragma unroll
      for (int j = 0; j < 4; ++j) {
        const int nrow = wn + j * 16 + (lane & 15);
        const int boff = nrow * 128 + ((kk * 64 + (lane >> 4) * 16) ^ ((nrow & 7) << 4));
        const bf16x8 bv = *(const bf16x8*)&sW[kb][boff];
        accA1[j] = __builtin_amdgcn_mfma_f32_16x16x32_bf16(av, bv, accA1[j], 0, 0, 0);
      }
    }
  }
  __syncthreads();          // all reads of ef-tile (sA) and sW done

  stageW(0, 0);             // first Phase-B panel into sW[0]

  // write pre_e results (bias+relu+bf16) into swizzled sA c-blocks
  {
    const int rowb = wm + ((lane >> 4) << 2);
#pragma unroll
    for (int h = 0; h < 2; ++h) {
#pragma unroll
      for (int j = 0; j < 4; ++j) {
        const int col  = h * 128 + wn + j * 16 + (lane & 15);  // 0..255
        const float bb = be[col];
        const int c    = col >> 6;
        const int cb2  = (col & 63) * 2;
#pragma unroll
        for (int r = 0; r < 4; ++r) {
          const int row = rowb + r;
          float v = (h == 0 ? accA0[j][r] : accA1[j][r]) + bb;
          v = v > 0.f ? v : 0.f;
          *(__hip_bfloat16*)&sA[c][row * 128 + (cb2 ^ ((row & 7) << 4))] =
              __float2bfloat16(v);
        }
      }
    }
  }

  asm volatile("s_waitcnt vmcnt(0)");
  __syncthreads();

  // ---- Phase B: 6-nt main loop ----
  int buf = 0;
  for (int nt = 0; nt < 6; ++nt) {
    const int mat = nt >> 1;
    f32x4 acc[4];
#pragma unroll
    for (int j = 0; j < 4; ++j) acc[j] = (f32x4)0.f;

#pragma unroll
    for (int c = 0; c < 4; ++c) {
      const int t = nt * 4 + c;
      if (t + 1 < 24) stageW(buf ^ 1, t + 1);
#pragma unroll
      for (int kk = 0; kk < 2; ++kk) {
        const int row  = wm + (lane & 15);
        const int aoff = row * 128 + ((kk * 64 + (lane >> 4) * 16) ^ ((row & 7) << 4));
        const bf16x8 av = *(const bf16x8*)&sA[c][aoff];
        bf16x8 bv[4];
#pragma unroll
        for (int j = 0; j < 4; ++j) {
          const int nrow = wn + j * 16 + (lane & 15);
          const int boff = nrow * 128 + ((kk * 64 + (lane >> 4) * 16) ^ ((nrow & 7) << 4));
          bv[j] = *(const bf16x8*)&sW[buf][boff];
        }
#pragma unroll
        for (int j = 0; j < 4; ++j)
          acc[j] = __builtin_amdgcn_mfma_f32_16x16x32_bf16(av, bv[j], acc[j], 0, 0, 0);
      }
      __syncthreads();
      buf ^= 1;
    }

    // epilogue (direct from acc)
    const int colbase = (nt & 1) * 128 + wn;
    const int lrow = wm + ((lane >> 4) << 2);
#pragma unroll
    for (int j = 0; j < 4; ++j) {
      const int col = colbase + j * 16 + (lane & 15);
      if (mat == 0) {
        const float bb = bpa[col];
#pragma unroll
        for (int r = 0; r < 4; ++r) {
          const int le = lrow + r;
          float v = acc[j][r] + bb +
                    __bfloat162float(nodeP[(size_t)sSrc[le] * 1024 + col]);
          v = v > 0.f ? v : 0.f;
          if (MSG) msg_p[(size_t)sPin[le] * 256 + col] = __float2bfloat16(v);
          else     atomicAdd(&agg_p[(size_t)sDst[le] * 256 + col], v);
        }
      } else if (mat == 1) {
        const float bb = bsa[col];
#pragma unroll
        for (int r = 0; r < 4; ++r) {
          const int le = lrow + r;
          float v = acc[j][r] + bb +
                    __bfloat162float(nodeP[(size_t)sDst[le] * 1024 + 256 + col]);
          v = v > 0.f ? v : 0.f;
          if (MSG) msg_s[(size_t)sPout[le] * 256 + col] = __float2bfloat16(v);
          else     atomicAdd(&agg_s[(size_t)sSrc[le] * 256 + col], v);
        }
      } else {
        const float bb = bet[col];
#pragma unroll
        for (int r = 0; r < 4; ++r) {
          const int le = lrow + r;
          float v = acc[j][r] + bb +
                    __bfloat162float(nodeP[(size_t)sSrc[le] * 1024 + 512 + col]) +
                    __bfloat162float(nodeP[(size_t)sDst[le] * 1024 + 768 + col]);
          edge_out[(size_t)(e0 + le) * 256 + col] = v;
        }
      }
    }
  }
}

// ---------------------------------------------------------------------------
// CSR-ordered segment-sum + nodeH assembly, v2: 256 threads, 4-way row
// parallelism per direction (waves 0-1 -> P, waves 2-3 -> S); partials combine
// via shfl_xor(32) then a 2KB LDS exchange between the wave pair.
// ---------------------------------------------------------------------------
__global__ __launch_bounds__(256) void agg_kernel(
    const __hip_bfloat16* __restrict__ msg_p, const __hip_bfloat16* __restrict__ msg_s,
    const __hip_bfloat16* __restrict__ pre_n,
    const int* __restrict__ offs_in, const int* __restrict__ offs_out,
    __hip_bfloat16* __restrict__ nodeH) {
  __shared__ float part[2][32][8];   // [dir][cg][k] partial from odd wave

  const int v    = blockIdx.x;
  const int tid  = threadIdx.x;
  const int dir  = tid >> 7;         // 0: P, 1: S
  const int sub  = tid & 127;        // position within direction (2 waves)
  const int wsub = sub >> 6;         // wave within pair: 0/1
  const int lane = sub & 63;
  const int cg   = lane & 31;        // col group: cols cg*8..cg*8+7
  const int par  = wsub * 2 + (lane >> 5);  // 0..3 row parity

  const int* offs = dir ? offs_out : offs_in;
  const __hip_bfloat16* msg = dir ? msg_s : msg_p;

  const int p0 = offs[v], p1 = offs[v + 1];
  float acc[8];
#pragma unroll
  for (int k = 0; k < 8; ++k) acc[k] = 0.f;

  for (int i = p0 + par; i < p1; i += 4) {
    const uint4 u = *(const uint4*)(msg + (size_t)i * 256 + cg * 8);
    const unsigned short* h = (const unsigned short*)&u;
#pragma unroll
    for (int k = 0; k < 8; ++k) acc[k] += __uint_as_float((unsigned)h[k] << 16);
  }
  // combine parities within the wave (par pairs differ in lane bit 5)
#pragma unroll
  for (int k = 0; k < 8; ++k) acc[k] += __shfl_xor(acc[k], 32);

  // odd wave of the pair publishes its partial
  if (wsub == 1 && (lane >> 5) == 0) {
#pragma unroll
    for (int k = 0; k < 8; ++k) part[dir][cg][k] = acc[k];
  }
  __syncthreads();

  if (wsub == 0 && (lane >> 5) == 0) {
    const int deg = p1 - p0;
    const float inv = 1.f / (float)(deg > 1 ? deg : 1);
    union { __hip_bfloat16 h[8]; uint4 u; } o;
#pragma unroll
    for (int k = 0; k < 8; ++k)
      o.h[k] = __float2bfloat16((acc[k] + part[dir][cg][k]) * inv);
    *(uint4*)(nodeH + (size_t)v * 768 + dir * 512 + cg * 8) = o.u;
  } else if (wsub == 0 && dir == 0) {
    // middle third: pre_n copy (32 lanes, lane>>5 == 1)
    const uint4 u = *(const uint4*)(pre_n + (size_t)v * 256 + cg * 8);
    *(uint4*)(nodeH + (size_t)v * 768 + 256 + cg * 8) = u;
  }
}

// ---------------------------------------------------------------------------
// fallback node prep (atomic path)
// ---------------------------------------------------------------------------
__global__ void node_prep_kernel(const float* __restrict__ agg_p,
                                 const float* __restrict__ agg_s,
                                 const __hip_bfloat16* __restrict__ pre_n,
                                 const int* __restrict__ cnt_in,
                                 const int* __restrict__ cnt_out,
                                 __hip_bfloat16* __restrict__ nodeH) {
  const int row = blockIdx.x;
  const int c   = threadIdx.x;
  const float di = (float)(cnt_in[row]  > 1 ? cnt_in[row]  : 1);
  const float dd = (float)(cnt_out[row] > 1 ? cnt_out[row] : 1);
  nodeH[(size_t)row * 768 + c]       = __float2bfloat16(agg_p[(size_t)row * 256 + c] / di);
  nodeH[(size_t)row * 768 + 256 + c] = pre_n[(size_t)row * 256 + c];
  nodeH[(size_t)row * 768 + 512 + c] = __float2bfloat16(agg_s[(size_t)row * 256 + c] / dd);
}

// ---------------------------------------------------------------------------
extern "C" void kernel_launch(void* const* d_in, const int* in_sizes, int n_in,
                              void* d_out, int out_size, void* d_ws, size_t ws_size,
                              hipStream_t stream) {
  const float* x         = (const float*)d_in[0];
  const float* edge_feat = (const float*)d_in[1];
  const int*   edge_idx  = (const int*)d_in[2];
  const float* Wn  = (const float*)d_in[3];
  const float* bn  = (const float*)d_in[4];
  const float* We  = (const float*)d_in[5];
  const float* be  = (const float*)d_in[6];
  const float* Wpa = (const float*)d_in[7];
  const float* bpa = (const float*)d_in[8];
  const float* Wsa = (const float*)d_in[9];
  const float* bsa = (const float*)d_in[10];
  const float* Wnt = (const float*)d_in[11];
  const float* bnt = (const float*)d_in[12];
  const float* Wet = (const float*)d_in[13];
  const float* bet = (const float*)d_in[14];

  const int* src = edge_idx;
  const int* dst = edge_idx + N_EDGES;

  float* node_out = (float*)d_out;
  float* edge_out = (float*)d_out + (size_t)N_NODES * DD;

  char* p = (char*)d_ws;
  auto alloc = [&](size_t bytes) -> void* {
    void* r = (void*)p;
    p += (bytes + 255) & ~(size_t)255;
    return r;
  };

  __hip_bfloat16* pre_n_bf = (__hip_bfloat16*)alloc((size_t)N_NODES * DD * 2);
  __hip_bfloat16* nodeH    = (__hip_bfloat16*)alloc((size_t)N_NODES * 768 * 2);
  __hip_bfloat16* nodeP    = (__hip_bfloat16*)alloc((size_t)N_NODES * 1024 * 2);
  __hip_bfloat16* We_edge  = (__hip_bfloat16*)alloc((size_t)768 * 256 * 2);
  __hip_bfloat16* Wn_node  = (__hip_bfloat16*)alloc((size_t)1024 * 256 * 2);
  __hip_bfloat16* Wn_t     = (__hip_bfloat16*)alloc((size_t)256 * 256 * 2);
  __hip_bfloat16* We_t     = (__hip_bfloat16*)alloc((size_t)256 * 128 * 2);
  __hip_bfloat16* Wnt_t    = (__hip_bfloat16*)alloc((size_t)256 * 768 * 2);
  int* csr_zero = (int*)alloc(4 * (size_t)N_NODES * 4);
  int* cnt_in   = csr_zero;
  int* cnt_out  = csr_zero + N_NODES;
  int* cur_in   = csr_zero + 2 * N_NODES;
  int* cur_out  = csr_zero + 3 * N_NODES;
  int* offs_in  = (int*)alloc(((size_t)N_NODES + 1) * 4);
  int* offs_out = (int*)alloc(((size_t)N_NODES + 1) * 4);
  int* pos_in   = (int*)alloc((size_t)N_EDGES * 4);
  int* pos_out  = (int*)alloc((size_t)N_EDGES * 4);

  const size_t msg_bytes = (size_t)N_EDGES * DD * 2;
  const size_t base_used = (size_t)(p - (char*)d_ws);
  const bool msg_mode = ws_size >= base_used + 2 * msg_bytes + 512;

  __hip_bfloat16* msg_p = nullptr;
  __hip_bfloat16* msg_s = nullptr;
  float* agg_p = nullptr;
  float* agg_s = nullptr;
  if (msg_mode) {
    msg_p = (__hip_bfloat16*)alloc(msg_bytes);
    msg_s = (__hip_bfloat16*)alloc(msg_bytes);
  } else {
    agg_p = (float*)alloc((size_t)N_NODES * DD * 4);
    agg_s = (float*)alloc((size_t)N_NODES * DD * 4);
  }

  hipMemsetAsync(csr_zero, 0, 4 * (size_t)N_NODES * 4, stream);
  if (!msg_mode)
    hipMemsetAsync(agg_p, 0, 2 * (size_t)N_NODES * DD * 4, stream);

  prep_weights_kernel<<<(753664 + 255) / 256, 256, 0, stream>>>(
      Wn, We, Wnt, Wpa, Wsa, Wet, Wn_t, We_t, Wnt_t, We_edge, Wn_node);

  count_kernel<<<(N_EDGES + 255) / 256, 256, 0, stream>>>(src, dst, cnt_out, cnt_in);
  if (msg_mode) {
    scan2_kernel<<<2, 256, 0, stream>>>(cnt_in, cnt_out, offs_in, offs_out);
    fill_kernel<<<(N_EDGES + 255) / 256, 256, 0, stream>>>(
        src, dst, offs_out, offs_in, cur_out, cur_in, pos_out, pos_in);
  }

  {
    dim3 g((N_NODES + 127) / 128, 2);
    gemm_mfma_kernel<true, false, true><<<g, 512, 0, stream>>>(
        x, Wn_t, bn, nullptr, pre_n_bf, N_NODES, 4, 256);
  }
  {
    dim3 g((N_NODES + 127) / 128, 8);
    gemm_mfma_kernel<false, false, false><<<g, 512, 0, stream>>>(
        pre_n_bf, Wn_node, nullptr, nullptr, nodeP, N_NODES, 4, 1024);
  }

  if (msg_mode) {
    edge_mfma_kernel<true><<<N_EDGES / 64, 512, 0, stream>>>(
        edge_feat, We_t, be, We_edge, nodeP, src, dst, pos_in, pos_out,
        bpa, bsa, bet, nullptr, nullptr, msg_p, msg_s, edge_out);
    agg_kernel<<<N_NODES, 256, 0, stream>>>(
        msg_p, msg_s, pre_n_bf, offs_in, offs_out, nodeH);
  } else {
    edge_mfma_kernel<false><<<N_EDGES / 64, 512, 0, stream>>>(
        edge_feat, We_t, be, We_edge, nodeP, src, dst, nullptr, nullptr,
        bpa, bsa, bet, agg_p, agg_s, nullptr, nullptr, edge_out);
    node_prep_kernel<<<N_NODES, 256, 0, stream>>>(
        agg_p, agg_s, pre_n_bf, cnt_in, cnt_out, nodeH);
  }

  {
    dim3 g((N_NODES + 127) / 128, 2);
    gemm_mfma_kernel<false, true, false><<<g, 512, 0, stream>>>(
        nodeH, Wnt_t, bnt, node_out, nullptr, N_NODES, 12, 256);
  }
}